// Round 2
// baseline (708.531 us; speedup 1.0000x reference)
//
#include <hip/hip_runtime.h>

// ChunkedCrossAttention on MI355X (gfx950) — round 5.
// Changes vs round 4:
//  - gemm_kv's fused fp32-A reg-staging REMOVED: it serialized all 8 waves at
//    the ph4/ph8 barrier behind a 3-phase-lead fp32 HBM dependency (counters:
//    MfmaUtil 23%, VALU 13%, HBM 17% -> pure stall). ctx is now pre-cast to
//    bf16 (cast_k, pkbf RTZ = identical numerics) in two M-halves (ws fit),
//    and gemm_kv is a faithful m201 8-phase kernel: BOTH operands staged via
//    global_load_lds, 2 ldst16/thread/phase, vmcnt(4) gates at ph4/ph8 only.
//    Stage placement: A(t+1) at ph1-2 (buffer freed at prev ph8), B(t+2) at
//    ph3-4 / ph7-8, A(t+2) at ph5-6 — every buffer written >=2 barriers after
//    its last read; every read gated by a counted vmcnt.
//  - ws layout compacted; ctxb (64MB) overlays obuf (written only post-GEMM).
//  - prep_k, gemm_proj<0> (Q), attn, gemm_out unchanged.

#define DEV __device__ __forceinline__

typedef __bf16 bf16x8 __attribute__((ext_vector_type(8)));
typedef float f32x4 __attribute__((ext_vector_type(4)));

DEV unsigned short f2bf(float f) {
  union { float f; unsigned int u; } v; v.f = f;
  unsigned int u = v.u;
  unsigned int r = (u + 0x7FFFu + ((u >> 16) & 1u)) >> 16;  // RNE
  return (unsigned short)r;
}
DEV float bf2f(unsigned short h) {
  union { unsigned int u; float f; } v; v.u = ((unsigned int)h) << 16;
  return v.f;
}
// pack two fp32 -> two bf16 (RTZ): result = [bf16(lo), bf16(hi)]
DEV unsigned int pkbf(unsigned int hi, unsigned int lo) {
  return __builtin_amdgcn_perm(hi, lo, 0x07060302u);
}

// async global->LDS, 16B per lane; LDS dest = wave-uniform base + lane*16
DEV void ldst16(const void* g, void* l) {
  __builtin_amdgcn_global_load_lds(
      (const __attribute__((address_space(1))) void*)g,
      (__attribute__((address_space(3))) void*)l, 16, 0, 0);
}

DEV void bar() { __builtin_amdgcn_s_barrier(); }
#define VMCNT4 asm volatile("s_waitcnt vmcnt(4)" ::: "memory")
#define VMCNT0 asm volatile("s_waitcnt vmcnt(0)" ::: "memory")

// ---------------------------------------------------------------------------
// prep: weight transpose+cast (+SCALE fold) via LDS tiles, zero rows 0..62
// per batch of out, rope cos/sin tables. One launch, grid 796.
// ---------------------------------------------------------------------------
__global__ __launch_bounds__(256) void prep_k(const float* __restrict__ Wq,
                                              const float* __restrict__ Wk,
                                              const float* __restrict__ Wv,
                                              const float* __restrict__ Wo,
                                              const float* __restrict__ qpe,
                                              const float* __restrict__ kpe,
                                              unsigned short* __restrict__ Wqt,
                                              unsigned short* __restrict__ Wkt,
                                              unsigned short* __restrict__ Wvt,
                                              unsigned short* __restrict__ Wot,
                                              float* __restrict__ ck, float* __restrict__ sk,
                                              float* __restrict__ cq, float* __restrict__ sq,
                                              float* __restrict__ out) {
  __shared__ float tl[64][65];
  int blk = blockIdx.x;
  int tid = threadIdx.x;
  if (blk < 512) {
    int mat = blk >> 7, loc = blk & 127;
    const float* W;
    unsigned short* Wt;
    int R, C;
    float scale = 1.0f;
    if (mat == 0)      { W = Wq; Wt = Wqt; R = 1024; C = 512; scale = 0.125f; }
    else if (mat == 1) { W = Wk; Wt = Wkt; R = 1024; C = 512; }
    else if (mat == 2) { W = Wv; Wt = Wvt; R = 1024; C = 512; }
    else               { W = Wo; Wt = Wot; R = 512;  C = 1024; }
    int nct = C >> 6;
    int rt = loc / nct, ct = loc % nct;
    int r0 = rt << 6, c0 = ct << 6;
    #pragma unroll
    for (int i = 0; i < 16; ++i) {
      int flat = i * 256 + tid;
      int rr = flat >> 6, cc = flat & 63;
      tl[rr][cc] = W[(size_t)(r0 + rr) * C + c0 + cc] * scale;
    }
    __syncthreads();
    #pragma unroll
    for (int i = 0; i < 16; ++i) {
      int flat = i * 256 + tid;
      int cc = flat >> 6, rr = flat & 63;
      Wt[(size_t)(c0 + cc) * R + r0 + rr] = f2bf(tl[rr][cc]);
    }
  } else if (blk < 764) {                  // zero rows 0..62 of each batch
    int r = blk - 512;
    int b = r / 63, rr = r % 63;
    float4 z = {0.f, 0.f, 0.f, 0.f};
    *(float4*)(out + (((size_t)(b * 4096 + rr)) << 10) + tid * 4) = z;
  } else {                                 // rope tables
    int t = (blk - 764) * 256 + tid;       // 0..8191
    float f = kpe[t];
    ck[t] = cosf(f);
    sk[t] = sinf(f);
    if (t < 64) {
      float g = qpe[63 * 64 + t];
      cq[t] = cosf(g);
      sq[t] = sinf(g);
    }
  }
}

// ---------------------------------------------------------------------------
// cast_k: fp32 -> bf16 (RTZ pack), 2048 elts/block. Pure streaming.
// ---------------------------------------------------------------------------
__global__ __launch_bounds__(256) void cast_k(const float* __restrict__ src,
                                              unsigned short* __restrict__ dst) {
  size_t base = ((size_t)blockIdx.x * 256 + threadIdx.x) * 8;
  uint4 lo = *(const uint4*)(src + base);
  uint4 hi = *(const uint4*)(src + base + 4);
  uint4 pk;
  pk.x = pkbf(lo.y, lo.x);
  pk.y = pkbf(lo.w, lo.z);
  pk.z = pkbf(hi.y, hi.x);
  pk.w = pkbf(hi.w, hi.z);
  *(uint4*)(dst + base) = pk;
}

// ---------------------------------------------------------------------------
// Q projection (unchanged): C(Mx512) = cast(Af)(MxK) * B^T(512xK); A
// reg-staged fp32->bf16 pack, B via global_load_lds; RoPE-Q on rows m%64==0.
// ---------------------------------------------------------------------------
template <int MODE>
__global__ __launch_bounds__(256) void gemm_proj(const float* __restrict__ Af,
                                                 const unsigned short* __restrict__ B0,
                                                 const unsigned short* __restrict__ B1,
                                                 unsigned short* __restrict__ out0,
                                                 unsigned short* __restrict__ out1,
                                                 const float* __restrict__ ck,
                                                 const float* __restrict__ sk,
                                                 const float* __restrict__ cq,
                                                 const float* __restrict__ sq) {
  __shared__ unsigned short sh[16384];  // As = sh[0:8192], Bs = sh[8192:16384]
  unsigned short* As = sh;
  unsigned short* Bs = sh + 8192;
  const int K = 1024;

  int id = blockIdx.x;
  int x, y, z;
  if (MODE == 0) { x = (id & 7) + 8 * (id >> 5); y = (id >> 3) & 3; z = 0; }
  else           { x = (id & 7) + 8 * (id >> 6); int j = (id >> 3) & 7; y = j & 3; z = j >> 2; }
  const unsigned short* B = z ? B1 : B0;
  int m0 = x * 128, n0 = y * 128;
  int tid = threadIdx.x, w = tid >> 6, lane = tid & 63;
  int wm = (w & 1) * 64, wn = (w >> 1) * 64;
  int Lrow = lane >> 3, Lc = lane & 7;
  int srcC = Lc ^ (Lrow & 7);

  const float* asrc[4];
  bool avalid[4];
  #pragma unroll
  for (int q = 0; q < 4; ++q) {
    int t = w * 4 + q;
    int gm = m0 + t * 8 + Lrow;
    if (MODE == 0) {
      int b = gm >> 12, p = gm & 4095;
      avalid[q] = (p <= 4032);
      asrc[q] = Af + (((size_t)(b << 12) + p + 63) << 10) + srcC * 8;
    } else {
      avalid[q] = true;
      asrc[q] = Af + (size_t)gm * 1024 + srcC * 8;
    }
  }

  f32x4 acc[4][4] = {};

  for (int k0 = 0; k0 < K; k0 += 64) {
    #pragma unroll
    for (int q = 0; q < 4; ++q) {
      int t = w * 4 + q;
      uint4 lo = {0, 0, 0, 0}, hi = {0, 0, 0, 0};
      if (avalid[q]) {
        lo = *(const uint4*)(asrc[q] + k0);
        hi = *(const uint4*)(asrc[q] + k0 + 4);
      }
      uint4 pk;
      pk.x = pkbf(lo.y, lo.x);
      pk.y = pkbf(lo.w, lo.z);
      pk.z = pkbf(hi.y, hi.x);
      pk.w = pkbf(hi.w, hi.z);
      *(uint4*)((char*)As + t * 1024 + lane * 16) = pk;
      ldst16(B + (size_t)(n0 + t * 8 + Lrow) * K + (k0 + srcC * 8), (char*)Bs + t * 1024);
    }
    __syncthreads();
    #pragma unroll
    for (int k32 = 0; k32 < 2; ++k32) {
      int c = k32 * 4 + (lane >> 4);
      bf16x8 af[4], bfr[4];
      #pragma unroll
      for (int mt = 0; mt < 4; ++mt) {
        int m = wm + mt * 16 + (lane & 15);
        af[mt] = *(const bf16x8*)((const char*)As + m * 128 + (c ^ (m & 7)) * 16);
      }
      #pragma unroll
      for (int nt = 0; nt < 4; ++nt) {
        int n = wn + nt * 16 + (lane & 15);
        bfr[nt] = *(const bf16x8*)((const char*)Bs + n * 128 + (c ^ (n & 7)) * 16);
      }
      #pragma unroll
      for (int mt = 0; mt < 4; ++mt)
        #pragma unroll
        for (int nt = 0; nt < 4; ++nt)
          acc[mt][nt] = __builtin_amdgcn_mfma_f32_16x16x32_bf16(af[mt], bfr[nt], acc[mt][nt], 0, 0, 0);
    }
    __syncthreads();
  }

  // C/D layout: col = lane&15, row = (lane>>4)*4 + reg.
  if (MODE == 0) {
    #pragma unroll
    for (int mt = 0; mt < 4; ++mt)
      #pragma unroll
      for (int nt = 0; nt < 4; ++nt)
        #pragma unroll
        for (int r = 0; r < 4; ++r) {
          int m = m0 + wm + mt * 16 + (lane >> 4) * 4 + r;
          int n = n0 + wn + nt * 16 + (lane & 15);
          float val = acc[mt][nt][r];
          if ((m & 63) == 0) {  // only chunk-row 0 gets Q-RoPE
            int d = nt * 16 + (lane & 15);
            float partner = acc[mt][nt ^ 2][r];
            val = val * cq[d] + (nt < 2 ? -partner : partner) * sq[d];
          }
          out0[(size_t)m * 512 + n] = f2bf(val);
        }
  } else if (z == 0) {
    #pragma unroll
    for (int mt = 0; mt < 4; ++mt)
      #pragma unroll
      for (int r = 0; r < 4; ++r) {
        int m = m0 + wm + mt * 16 + (lane >> 4) * 4 + r;
        int fib = (m & 127) * 64;
        #pragma unroll
        for (int nt = 0; nt < 4; ++nt) {
          int n = n0 + wn + nt * 16 + (lane & 15);
          int d = nt * 16 + (lane & 15);
          float partner = acc[mt][nt ^ 2][r];
          float val = acc[mt][nt][r] * ck[fib + d] + (nt < 2 ? -partner : partner) * sk[fib + d];
          out0[(size_t)m * 512 + n] = f2bf(val);
        }
      }
  } else {
    #pragma unroll
    for (int mt = 0; mt < 4; ++mt)
      #pragma unroll
      for (int nt = 0; nt < 4; ++nt)
        #pragma unroll
        for (int r = 0; r < 4; ++r) {
          int ml = wm + mt * 16 + (lane >> 4) * 4 + r;
          int nl = wn + nt * 16 + (lane & 15);
          int mc = ml >> 3, me = ml & 7;
          *(unsigned short*)((char*)sh + nl * 256 + ((mc ^ (nl & 15)) * 16) + me * 2) =
              f2bf(acc[mt][nt][r]);
        }
    __syncthreads();
    #pragma unroll
    for (int i = 0; i < 8; ++i) {
      int flat = i * 256 + tid;
      int nl = flat >> 4, mc = flat & 15;
      uint4 v = *(const uint4*)((const char*)sh + nl * 256 + ((mc ^ (nl & 15)) * 16));
      *(uint4*)(out1 + (size_t)(n0 + nl) * 65536 + m0 + mc * 8) = v;
    }
  }
}

// ---------------------------------------------------------------------------
// gemm_kv: K/V projection over an M-half (32768 rows), 256x256 tile, BK=64,
// 8 waves, m201-faithful 8-phase schedule, all-gload_lds staging (bf16 A from
// ctxb). LDS: A0|A1|B0|B1, 32KB each, swizzled chunk layout
//   phys_chunk(row,c) = row*8 + (c ^ (row&7)), chunk = 16B.
// Per phase: {4-12 ds_read_b128 | 2 ldst16} -> bar -> setprio(1) 16 MFMA
// setprio(0) -> bar.  vmcnt(4) at ph4/ph8 only.
// Stage placement (iteration it = tiles t0=2it on A0/B0, t1=2it+1 on A1/B1):
//   ph1-2: A(t1)->A1 (A1 freed prev ph8; consumed ph5, gated ph4)
//   ph3-4: B(t0+2)->B0 (freed ph1; consumed next ph1, gated next GATE)
//   ph5-6: A(t0+2)->A0 (freed ph4; consumed next ph1)
//   ph7-8: B(t1+2)->B1 (freed ph5; consumed next ph5)
// FIFO check at each gate: outstanding = 12, vmcnt(4) completes exactly the
// tiles the next phase reads. Tail stages wrap k&1023 (junk, never consumed).
// ---------------------------------------------------------------------------
DEV bf16x8 rdfrag(const unsigned short* b, int row, int c) {
  return *(const bf16x8*)((const char*)b + row * 128 + ((c ^ (row & 7)) << 4));
}

DEV void rdA(const unsigned short* bufA, int wm, int ln15, int l4, int mtb,
             bf16x8 (&af)[2][2]) {
  #pragma unroll
  for (int mq = 0; mq < 2; ++mq)
    #pragma unroll
    for (int kk = 0; kk < 2; ++kk)
      af[mq][kk] = rdfrag(bufA, wm + (mtb + mq) * 16 + ln15, kk * 4 + l4);
}

DEV void rdB(const unsigned short* bufB, int wn, int ln15, int l4, bf16x8 (&bf)[4][2]) {
  #pragma unroll
  for (int nt = 0; nt < 4; ++nt)
    #pragma unroll
    for (int kk = 0; kk < 2; ++kk)
      bf[nt][kk] = rdfrag(bufB, wn + nt * 16 + ln15, kk * 4 + l4);
}

template <int MTB>
DEV void mfma16(const bf16x8 (&af)[2][2], const bf16x8 (&bf)[4][2], f32x4 (&acc)[8][4]) {
  __builtin_amdgcn_s_setprio(1);
  #pragma unroll
  for (int mq = 0; mq < 2; ++mq)
    #pragma unroll
    for (int nt = 0; nt < 4; ++nt)
      #pragma unroll
      for (int kk = 0; kk < 2; ++kk)
        acc[MTB + mq][nt] = __builtin_amdgcn_mfma_f32_16x16x32_bf16(
            af[mq][kk], bf[nt][kk], acc[MTB + mq][nt], 0, 0, 0);
  __builtin_amdgcn_s_setprio(0);
}

// stage half-tile h (rows [128h,128h+128)) of a 256x64 bf16 tile: 2 ldst16
DEV void stg(unsigned short* buf, const unsigned short* src, int r0, int w,
             int Lrow, int srcC, int k0, int h) {
  #pragma unroll
  for (int qq = 0; qq < 2; ++qq) {
    int q = 2 * h + qq;
    ldst16(src + (size_t)(r0 + q * 64 + w * 8 + Lrow) * 1024 + (k0 + srcC * 8),
           (char*)buf + ((q * 512 + w * 64) << 4));
  }
}

__global__ __launch_bounds__(512, 2) void gemm_kv(const unsigned short* __restrict__ Abf,
                                                  const unsigned short* __restrict__ Bk,
                                                  const unsigned short* __restrict__ Bv,
                                                  unsigned short* __restrict__ kb,
                                                  unsigned short* __restrict__ vtg,
                                                  const float* __restrict__ ck,
                                                  const float* __restrict__ sk,
                                                  int mbase) {
  __shared__ unsigned short sh[65536];  // 128 KiB
  unsigned short* A0b = sh;
  unsigned short* A1b = sh + 16384;
  unsigned short* B0b = sh + 32768;
  unsigned short* B1b = sh + 49152;

  int id = blockIdx.x;                      // 512 blocks
  int x = (id & 7) + 8 * (id >> 5);         // [0,128); 4 siblings same XCD
  int j = (id >> 3) & 3;
  int y = j & 1, z = j >> 1;
  const unsigned short* Bz = z ? Bv : Bk;
  int m0l = x << 8;                          // local row in Abf (this M-half)
  int m0 = mbase + m0l;                      // global row for outputs
  int n0 = y << 8;

  int tid = threadIdx.x, w = tid >> 6, lane = tid & 63;
  int wm = (w & 1) * 128, wn = (w >> 1) * 64;
  int ln15 = lane & 15, l4 = lane >> 4;
  int Lrow = lane >> 3;
  int srcC = (lane & 7) ^ (Lrow & 7);

  f32x4 acc[8][4] = {};

  // prologue: A(0)->A0, B(0)->B0, B(1)->B1; keep B(1)'s 4 loads in flight
  stg(A0b, Abf, m0l, w, Lrow, srcC, 0, 0);
  stg(A0b, Abf, m0l, w, Lrow, srcC, 0, 1);
  stg(B0b, Bz, n0, w, Lrow, srcC, 0, 0);
  stg(B0b, Bz, n0, w, Lrow, srcC, 0, 1);
  stg(B1b, Bz, n0, w, Lrow, srcC, 64, 0);
  stg(B1b, Bz, n0, w, Lrow, srcC, 64, 1);
  VMCNT4;
  bar();

  for (int it = 0; it < 8; ++it) {
    const int k0 = it * 128;
    bf16x8 af[2][2], bf[4][2];

    // ---- tile t0 = 2it (A0b/B0b) ----
    rdB(B0b, wn, ln15, l4, bf);
    rdA(A0b, wm, ln15, l4, 0, af);
    stg(A1b, Abf, m0l, w, Lrow, srcC, k0 + 64, 0);           // A(t1) h0
    bar(); mfma16<0>(af, bf, acc); bar();

    rdA(A0b, wm, ln15, l4, 2, af);
    stg(A1b, Abf, m0l, w, Lrow, srcC, k0 + 64, 1);           // A(t1) h1
    bar(); mfma16<2>(af, bf, acc); bar();

    rdA(A0b, wm, ln15, l4, 4, af);
    stg(B0b, Bz, n0, w, Lrow, srcC, (k0 + 128) & 1023, 0);   // B(t0+2) h0
    bar(); mfma16<4>(af, bf, acc); bar();

    rdA(A0b, wm, ln15, l4, 6, af);
    stg(B0b, Bz, n0, w, Lrow, srcC, (k0 + 128) & 1023, 1);   // B(t0+2) h1
    VMCNT4;                    // completes B(t1)+A(t1); leaves B(t0+2) flying
    bar(); mfma16<6>(af, bf, acc); bar();

    // ---- tile t1 = 2it+1 (A1b/B1b) ----
    rdB(B1b, wn, ln15, l4, bf);
    rdA(A1b, wm, ln15, l4, 0, af);
    stg(A0b, Abf, m0l, w, Lrow, srcC, (k0 + 128) & 1023, 0); // A(t0+2) h0
    bar(); mfma16<0>(af, bf, acc); bar();

    rdA(A1b, wm, ln15, l4, 2, af);
    stg(A0b, Abf, m0l, w, Lrow, srcC, (k0 + 128) & 1023, 1); // A(t0+2) h1
    bar(); mfma16<2>(af, bf, acc); bar();

    rdA(A1b, wm, ln15, l4, 4, af);
    stg(B1b, Bz, n0, w, Lrow, srcC, (k0 + 192) & 1023, 0);   // B(t1+2) h0
    bar(); mfma16<4>(af, bf, acc); bar();

    rdA(A1b, wm, ln15, l4, 6, af);
    stg(B1b, Bz, n0, w, Lrow, srcC, (k0 + 192) & 1023, 1);   // B(t1+2) h1
    VMCNT4;                    // completes A(t0+2); leaves B(t1+2) flying
    bar(); mfma16<6>(af, bf, acc); bar();
  }

  // drain wrapped tail stages before LDS reuse / exit
  VMCNT0;
  bar();

  if (z == 0) {  // K with RoPE: fi = (m&127)*64 + d
    #pragma unroll
    for (int mt = 0; mt < 8; ++mt)
      #pragma unroll
      for (int r = 0; r < 4; ++r) {
        int m = m0 + wm + mt * 16 + l4 * 4 + r;
        int fib = (m & 127) << 6;
        #pragma unroll
        for (int nt = 0; nt < 4; ++nt) {
          int d = nt * 16 + ln15;
          float partner = acc[mt][nt ^ 2][r];
          float val = acc[mt][nt][r] * ck[fib + d] + (nt < 2 ? -partner : partner) * sk[fib + d];
          kb[(size_t)m * 512 + n0 + wn + d] = f2bf(val);
        }
      }
  } else {  // V: transpose through LDS (256 rows x 512B), store vtg[n][m]
    #pragma unroll
    for (int mt = 0; mt < 8; ++mt)
      #pragma unroll
      for (int nt = 0; nt < 4; ++nt)
        #pragma unroll
        for (int r = 0; r < 4; ++r) {
          int ml = wm + mt * 16 + l4 * 4 + r;
          int nl = wn + nt * 16 + ln15;
          int mc = ml >> 3, me = ml & 7;
          *(unsigned short*)((char*)sh + nl * 512 + ((mc ^ (nl & 31)) << 4) + me * 2) =
              f2bf(acc[mt][nt][r]);
        }
    __syncthreads();
    #pragma unroll
    for (int i = 0; i < 16; ++i) {
      int flat = i * 512 + tid;
      int nl = flat >> 5, mc = flat & 31;
      uint4 v = *(const uint4*)((const char*)sh + nl * 512 + ((mc ^ (nl & 31)) << 4));
      *(uint4*)(vtg + (size_t)(n0 + nl) * 65536 + m0 + mc * 8) = v;
    }
  }
}

// ---------------------------------------------------------------------------
// Output GEMM (unchanged): out fp32 = A(16384x512) * Wo^T(1024x512) + bias,
// row-shifted: out[b, t+63] = row(b*4096+t) for t<=4032.
// ---------------------------------------------------------------------------
__global__ __launch_bounds__(256) void gemm_out(const unsigned short* __restrict__ A,
                                                const unsigned short* __restrict__ B,
                                                const float* __restrict__ bias,
                                                float* __restrict__ out) {
  __shared__ unsigned short sh[16384];
  unsigned short* As = sh;
  unsigned short* Bs = sh + 8192;
  const int K = 512, N = 1024;
  int id = blockIdx.x;
  int x = (id & 7) + 8 * (id >> 6), y = (id >> 3) & 7;
  int m0 = x * 128, n0 = y * 128;
  int tid = threadIdx.x, w = tid >> 6, lane = tid & 63;
  int wm = (w & 1) * 64, wn = (w >> 1) * 64;
  int Lrow = lane >> 3, Lc = lane & 7;
  int srcC = Lc ^ (Lrow & 7);

  f32x4 acc[4][4] = {};

  for (int k0 = 0; k0 < K; k0 += 64) {
    #pragma unroll
    for (int q = 0; q < 4; ++q) {
      int t = w * 4 + q;
      ldst16(A + (size_t)(m0 + t * 8 + Lrow) * K + (k0 + srcC * 8), (char*)As + t * 1024);
      ldst16(B + (size_t)(n0 + t * 8 + Lrow) * K + (k0 + srcC * 8), (char*)Bs + t * 1024);
    }
    __syncthreads();
    #pragma unroll
    for (int k32 = 0; k32 < 2; ++k32) {
      int c = k32 * 4 + (lane >> 4);
      bf16x8 af[4], bfr[4];
      #pragma unroll
      for (int mt = 0; mt < 4; ++mt) {
        int m = wm + mt * 16 + (lane & 15);
        af[mt] = *(const bf16x8*)((const char*)As + m * 128 + (c ^ (m & 7)) * 16);
      }
      #pragma unroll
      for (int nt = 0; nt < 4; ++nt) {
        int n = wn + nt * 16 + (lane & 15);
        bfr[nt] = *(const bf16x8*)((const char*)Bs + n * 128 + (c ^ (n & 7)) * 16);
      }
      #pragma unroll
      for (int mt = 0; mt < 4; ++mt)
        #pragma unroll
        for (int nt = 0; nt < 4; ++nt)
          acc[mt][nt] = __builtin_amdgcn_mfma_f32_16x16x32_bf16(af[mt], bfr[nt], acc[mt][nt], 0, 0, 0);
    }
    __syncthreads();
  }
  #pragma unroll
  for (int mt = 0; mt < 4; ++mt)
    #pragma unroll
    for (int nt = 0; nt < 4; ++nt)
      #pragma unroll
      for (int r = 0; r < 4; ++r) {
        int m = m0 + wm + mt * 16 + (lane >> 4) * 4 + r;
        int n = n0 + wn + nt * 16 + (lane & 15);
        int b = m >> 12, t = m & 4095;
        if (t <= 4032)
          out[((size_t)((b << 12) + t + 63)) * N + n] = acc[mt][nt][r] + bias[n];
      }
}

// ---------------------------------------------------------------------------
// Fused attention per (bc, h) (unchanged).
// ---------------------------------------------------------------------------
__global__ __launch_bounds__(256) void attn_kernel(const unsigned short* __restrict__ qb,
                                                   const unsigned short* __restrict__ kb,
                                                   const unsigned short* __restrict__ vtg,
                                                   const float* __restrict__ nullk,
                                                   const float* __restrict__ nullv,
                                                   unsigned short* __restrict__ ob) {
  __shared__ unsigned short qs[64 * 64];    // 8 KB  [i][d]
  __shared__ unsigned short ks[256 * 64];   // 32 KB [j][d]; reused as vt[d][j]
  __shared__ unsigned short ps[64 * 256];   // 32 KB [i][j]
  __shared__ float rnull[64];
  __shared__ float rsum[64];
  int id = blockIdx.x;
  int bc = (id & 7) + 8 * (id >> 6);
  int h = (id >> 3) & 7;
  int tid = threadIdx.x, w = tid >> 6, lane = tid & 63;
  int Lrow = lane >> 3, Lc = lane & 7, srcC = Lc ^ (Lrow & 7);

  #pragma unroll
  for (int q8 = 0; q8 < 2; ++q8) {
    int t = w * 2 + q8;
    ldst16(qb + (size_t)(bc * 64 + t * 8 + Lrow) * 512 + h * 64 + srcC * 8, (char*)qs + t * 1024);
  }
  #pragma unroll
  for (int q8 = 0; q8 < 8; ++q8) {
    int t = w * 8 + q8;
    ldst16(kb + (size_t)(bc * 256 + t * 8 + Lrow) * 512 + h * 64 + srcC * 8, (char*)ks + t * 1024);
  }
  __syncthreads();

  // null-key sims: 4 lanes per row, 16 d each, combine via shuffles.
  {
    int rl = lane >> 2, part = lane & 3;
    int row = w * 16 + rl;
    float s = 0.f;
    #pragma unroll
    for (int e = 0; e < 16; ++e) {
      int d = part * 16 + e;
      unsigned short qv = *(const unsigned short*)((const char*)qs + row * 128 +
                                                   (((d >> 3) ^ (row & 7)) * 16) + (d & 7) * 2);
      s += bf2f(qv) * nullk[h * 64 + d];
    }
    s += __shfl_xor(s, 1);
    s += __shfl_xor(s, 2);
    if (part == 0) rnull[row] = __expf(s);
  }

  // sim: wave w owns rows [16w,16w+16), 16 n-tiles of 16 keys.
  f32x4 acc[16] = {};
  #pragma unroll
  for (int k32 = 0; k32 < 2; ++k32) {
    int c = k32 * 4 + (lane >> 4);
    int m = w * 16 + (lane & 15);
    bf16x8 a = *(const bf16x8*)((const char*)qs + m * 128 + (c ^ (m & 7)) * 16);
    #pragma unroll
    for (int nt = 0; nt < 16; ++nt) {
      int n = nt * 16 + (lane & 15);
      bf16x8 b = *(const bf16x8*)((const char*)ks + n * 128 + (c ^ (n & 7)) * 16);
      acc[nt] = __builtin_amdgcn_mfma_f32_16x16x32_bf16(a, b, acc[nt], 0, 0, 0);
    }
  }

  // exp + row-sum (no max subtraction).
  int g = lane >> 4;
  #pragma unroll
  for (int r = 0; r < 4; ++r) {
    int row = w * 16 + g * 4 + r;
    float s = 0.f;
    #pragma unroll
    for (int nt = 0; nt < 16; ++nt) {
      float p = __expf(acc[nt][r]);
      acc[nt][r] = p;
      s += p;
    }
    s += __shfl_xor(s, 1);
    s += __shfl_xor(s, 2);
    s += __shfl_xor(s, 4);
    s += __shfl_xor(s, 8);
    if ((lane & 15) == 0) rsum[row] = s + rnull[row];
  }

  // P -> LDS bf16 (A-operand layout for PV).
  #pragma unroll
  for (int nt = 0; nt < 16; ++nt)
    #pragma unroll
    for (int r = 0; r < 4; ++r) {
      int row = w * 16 + g * 4 + r;
      int col = nt * 16 + (lane & 15);
      *(unsigned short*)((char*)ps + row * 512 + (((col >> 3) ^ (row & 7)) * 16) + (col & 7) * 2) =
          f2bf(acc[nt][r]);
    }
  __syncthreads();  // all waves done reading ks

  // stage V^T (pre-transposed in global) into ks via ldst16.
  #pragma unroll
  for (int q8 = 0; q8 < 8; ++q8) {
    int t = w * 8 + q8;                 // 1KB region = rows 2t, 2t+1
    int dd = t * 2 + (lane >> 5);
    int cl = (lane & 31) ^ (dd & 7);    // logical chunk for this phys slot
    ldst16(vtg + (size_t)(h * 64 + dd) * 65536 + bc * 256 + cl * 8, (char*)ks + t * 1024);
  }
  __syncthreads();

  // o = P v : k over 256 keys, 4 n-tiles of d.
  f32x4 oacc[4] = {};
  #pragma unroll
  for (int k32 = 0; k32 < 8; ++k32) {
    int c = k32 * 4 + (lane >> 4);
    int m = w * 16 + (lane & 15);
    bf16x8 a = *(const bf16x8*)((const char*)ps + m * 512 + (c ^ (m & 7)) * 16);
    #pragma unroll
    for (int nt = 0; nt < 4; ++nt) {
      int n = nt * 16 + (lane & 15);
      bf16x8 b = *(const bf16x8*)((const char*)ks + n * 512 + (c ^ (n & 7)) * 16);
      oacc[nt] = __builtin_amdgcn_mfma_f32_16x16x32_bf16(a, b, oacc[nt], 0, 0, 0);
    }
  }
  #pragma unroll
  for (int nt = 0; nt < 4; ++nt)
    #pragma unroll
    for (int r = 0; r < 4; ++r) {
      int row = w * 16 + g * 4 + r;
      int d = nt * 16 + (lane & 15);
      float o = oacc[nt][r] + rnull[row] * nullv[h * 64 + d];
      o /= rsum[row];
      ob[((size_t)(bc * 64 + row) * 8 + h) * 64 + d] = f2bf(o);
    }
}

// ---------------------------------------------------------------------------
extern "C" void kernel_launch(void* const* d_in, const int* in_sizes, int n_in,
                              void* d_out, int out_size, void* d_ws, size_t ws_size,
                              hipStream_t stream) {
  const float* x = (const float*)d_in[0];
  const float* ctx = (const float*)d_in[1];
  const float* qpe = (const float*)d_in[2];
  const float* kpe = (const float*)d_in[3];
  const float* Wq = (const float*)d_in[4];
  const float* Wk = (const float*)d_in[5];
  const float* Wv = (const float*)d_in[6];
  const float* Wo = (const float*)d_in[7];
  const float* bo = (const float*)d_in[8];
  const float* nk = (const float*)d_in[9];
  const float* nv = (const float*)d_in[10];
  float* out = (float*)d_out;
  char* ws = (char*)d_ws;

  unsigned short* Wqt  = (unsigned short*)(ws + 0);          // 1,048,576
  unsigned short* Wkt  = (unsigned short*)(ws + 1048576);    // 1,048,576
  unsigned short* Wvt  = (unsigned short*)(ws + 2097152);    // 1,048,576
  unsigned short* Wot  = (unsigned short*)(ws + 3145728);    // 1,048,576
  float* cosk = (float*)(ws + 4194304);                      // 32,768
  float* sink = (float*)(ws + 4227072);                      // 32,768
  float* cosq = (float*)(ws + 4259840);                      // 256
  float* sinq = (float*)(ws + 4260096);                      // 256
  unsigned short* qb   = (unsigned short*)(ws + 4260352);    // 16,777,216
  unsigned short* kb   = (unsigned short*)(ws + 21037568);   // 67,108,864
  unsigned short* vtg  = (unsigned short*)(ws + 88146432);   // 67,108,864 (V^T: [512][65536])
  unsigned short* obuf = (unsigned short*)(ws + 155255296);  // 16,777,216 (overlays ctxb)
  unsigned short* ctxb = (unsigned short*)(ws + 155255296);  // 67,108,864 (dead before attn)
  // peak ws use: 222,364,160 B

  prep_k<<<796, 256, 0, stream>>>(Wq, Wk, Wv, Wo, qpe, kpe, Wqt, Wkt, Wvt, Wot,
                                  cosk, sink, cosq, sinq, out);

  // Q projection (16384x1024)@(1024x512), fp32-A fused cast + shift, RoPE fused
  gemm_proj<0><<<512, 256, 0, stream>>>(x, Wqt, Wqt, qb, nullptr,
                                        cosk, sink, cosq, sinq);

  // K+V projection in two M-halves: cast ctx half -> bf16, then 8-phase GEMM
  cast_k<<<16384, 256, 0, stream>>>(ctx, ctxb);
  gemm_kv<<<512, 512, 0, stream>>>(ctxb, Wkt, Wvt, kb, vtg, cosk, sink, 0);
  cast_k<<<16384, 256, 0, stream>>>(ctx + 33554432, ctxb);
  gemm_kv<<<512, 512, 0, stream>>>(ctxb, Wkt, Wvt, kb, vtg, cosk, sink, 32768);

  attn_kernel<<<2048, 256, 0, stream>>>(qb, kb, vtg, nk, nv, obuf);

  // Output: (16384x512)@(512x1024) + bias, shifted rows
  gemm_out<<<1024, 256, 0, stream>>>(obuf, Wot, bo, out);
}

// Round 3
// 673.823 us; speedup vs baseline: 1.0515x; 1.0515x over previous
//
#include <hip/hip_runtime.h>

// ChunkedCrossAttention on MI355X (gfx950) — round 6.
// Changes vs round 5:
//  - ONE 8-phase GEMM engine (kloop8<KD>) now drives Q, K, V projections
//    (merged into a single 1152-block launch, K=1024) AND the output GEMM
//    (256 blocks, K=512). Q's fp32 reg-staging stall is gone: x is
//    pre-shifted+cast by cast_all, so all GEMM operands are bf16 via
//    global_load_lds with counted vmcnt gates.
//  - cast_all: single streaming pass casts ctx->ctxb and builds xb
//    (row-shifted by 63, zero-padded) — ws is 1 GiB (fill evidence), no
//    overlays needed. 9 launches -> 5.
//  - attn restructured: swapped QK^T (mfma(K,Q) — same LDS reads, swapped
//    operands) puts P in [j][q] layout; P->LDS = 16 b64 writes (was 64 b16);
//    V^T prefetched at kernel start into its own buffer (ps overlays ks
//    after one barrier; LDS stays 72KB -> 2 blocks/CU); row-sum/null-sim
//    in-register via shfl_xor(16/32); packed 8B output stores; 3 barriers->2.

#define DEV __device__ __forceinline__

typedef __bf16 bf16x8 __attribute__((ext_vector_type(8)));
typedef float f32x4 __attribute__((ext_vector_type(4)));

DEV unsigned short f2bf(float f) {
  union { float f; unsigned int u; } v; v.f = f;
  unsigned int u = v.u;
  unsigned int r = (u + 0x7FFFu + ((u >> 16) & 1u)) >> 16;  // RNE
  return (unsigned short)r;
}
DEV float bf2f(unsigned short h) {
  union { unsigned int u; float f; } v; v.u = ((unsigned int)h) << 16;
  return v.f;
}
DEV float bfelem(bf16x8 v, int i) {
  union { bf16x8 v; unsigned short u[8]; } t; t.v = v;
  return bf2f(t.u[i]);
}
// pack two fp32 -> two bf16 (RTZ): result = [bf16(lo), bf16(hi)]
DEV unsigned int pkbf(unsigned int hi, unsigned int lo) {
  return __builtin_amdgcn_perm(hi, lo, 0x07060302u);
}
// RNE pair pack
DEV unsigned int pk2(float lo, float hi) {
  return ((unsigned int)f2bf(hi) << 16) | f2bf(lo);
}

// async global->LDS, 16B per lane; LDS dest = wave-uniform base + lane*16
DEV void ldst16(const void* g, void* l) {
  __builtin_amdgcn_global_load_lds(
      (const __attribute__((address_space(1))) void*)g,
      (__attribute__((address_space(3))) void*)l, 16, 0, 0);
}

DEV void bar() { __builtin_amdgcn_s_barrier(); }
#define VMCNT4 asm volatile("s_waitcnt vmcnt(4)" ::: "memory")
#define VMCNT0 asm volatile("s_waitcnt vmcnt(0)" ::: "memory")

// ---------------------------------------------------------------------------
// prep: weight transpose+cast (+SCALE fold) via LDS tiles, zero rows 0..62
// per batch of out, rope cos/sin tables. One launch, grid 796.
// ---------------------------------------------------------------------------
__global__ __launch_bounds__(256) void prep_k(const float* __restrict__ Wq,
                                              const float* __restrict__ Wk,
                                              const float* __restrict__ Wv,
                                              const float* __restrict__ Wo,
                                              const float* __restrict__ qpe,
                                              const float* __restrict__ kpe,
                                              unsigned short* __restrict__ Wqt,
                                              unsigned short* __restrict__ Wkt,
                                              unsigned short* __restrict__ Wvt,
                                              unsigned short* __restrict__ Wot,
                                              float* __restrict__ ck, float* __restrict__ sk,
                                              float* __restrict__ cq, float* __restrict__ sq,
                                              float* __restrict__ out) {
  __shared__ float tl[64][65];
  int blk = blockIdx.x;
  int tid = threadIdx.x;
  if (blk < 512) {
    int mat = blk >> 7, loc = blk & 127;
    const float* W;
    unsigned short* Wt;
    int R, C;
    float scale = 1.0f;
    if (mat == 0)      { W = Wq; Wt = Wqt; R = 1024; C = 512; scale = 0.125f; }
    else if (mat == 1) { W = Wk; Wt = Wkt; R = 1024; C = 512; }
    else if (mat == 2) { W = Wv; Wt = Wvt; R = 1024; C = 512; }
    else               { W = Wo; Wt = Wot; R = 512;  C = 1024; }
    int nct = C >> 6;
    int rt = loc / nct, ct = loc % nct;
    int r0 = rt << 6, c0 = ct << 6;
    #pragma unroll
    for (int i = 0; i < 16; ++i) {
      int flat = i * 256 + tid;
      int rr = flat >> 6, cc = flat & 63;
      tl[rr][cc] = W[(size_t)(r0 + rr) * C + c0 + cc] * scale;
    }
    __syncthreads();
    #pragma unroll
    for (int i = 0; i < 16; ++i) {
      int flat = i * 256 + tid;
      int cc = flat >> 6, rr = flat & 63;
      Wt[(size_t)(c0 + cc) * R + r0 + rr] = f2bf(tl[rr][cc]);
    }
  } else if (blk < 764) {                  // zero rows 0..62 of each batch
    int r = blk - 512;
    int b = r / 63, rr = r % 63;
    float4 z = {0.f, 0.f, 0.f, 0.f};
    *(float4*)(out + (((size_t)(b * 4096 + rr)) << 10) + tid * 4) = z;
  } else {                                 // rope tables
    int t = (blk - 764) * 256 + tid;       // 0..8191
    float f = kpe[t];
    ck[t] = cosf(f);
    sk[t] = sinf(f);
    if (t < 64) {
      float g = qpe[63 * 64 + t];
      cq[t] = cosf(g);
      sq[t] = sinf(g);
    }
  }
}

// ---------------------------------------------------------------------------
// cast_all: ctx fp32 -> ctxb bf16 (flat, 67.1M elts, blocks [0,32768)), and
// x fp32 -> xb bf16 row-shifted by 63 + zero-pad (16.7M elts, blocks
// [32768,40960)). RTZ pack (pkbf), 2048 elts/block.
// ---------------------------------------------------------------------------
__global__ __launch_bounds__(256) void cast_all(const float* __restrict__ ctx,
                                                const float* __restrict__ x,
                                                unsigned short* __restrict__ ctxb,
                                                unsigned short* __restrict__ xb) {
  int id = blockIdx.x;
  if (id < 32768) {
    size_t base = ((size_t)id * 256 + threadIdx.x) * 8;
    uint4 lo = *(const uint4*)(ctx + base);
    uint4 hi = *(const uint4*)(ctx + base + 4);
    uint4 pk;
    pk.x = pkbf(lo.y, lo.x);
    pk.y = pkbf(lo.w, lo.z);
    pk.z = pkbf(hi.y, hi.x);
    pk.w = pkbf(hi.w, hi.z);
    *(uint4*)(ctxb + base) = pk;
  } else {
    size_t e = ((size_t)(id - 32768) * 256 + threadIdx.x) * 8;
    int m = (int)(e >> 10), c = (int)(e & 1023);
    int b = m >> 12, t = m & 4095;
    uint4 pk = {0, 0, 0, 0};
    if (t <= 4032) {
      const float* s = x + (((size_t)(b << 12) + t + 63) << 10) + c;
      uint4 lo = *(const uint4*)s;
      uint4 hi = *(const uint4*)(s + 4);
      pk.x = pkbf(lo.y, lo.x);
      pk.y = pkbf(lo.w, lo.z);
      pk.z = pkbf(hi.y, hi.x);
      pk.w = pkbf(hi.w, hi.z);
    }
    *(uint4*)(xb + e) = pk;
  }
}

// ---------------------------------------------------------------------------
// 8-phase 256x256 GEMM engine (BK=64, 8 waves, 128KB LDS, counted vmcnt).
// LDS: A0|A1|B0|B1, 32KB each, swizzled chunk layout
//   phys_chunk(row,c) = row*8 + (c ^ (row&7)), chunk = 16B.
// ---------------------------------------------------------------------------
DEV bf16x8 rdfrag(const unsigned short* b, int row, int c) {
  return *(const bf16x8*)((const char*)b + row * 128 + ((c ^ (row & 7)) << 4));
}
DEV bf16x8 rdfrag512(const unsigned short* b, int row, int c) {
  return *(const bf16x8*)((const char*)b + row * 512 + ((c ^ (row & 7)) << 4));
}

DEV void rdA(const unsigned short* bufA, int wm, int ln15, int l4, int mtb,
             bf16x8 (&af)[2][2]) {
  #pragma unroll
  for (int mq = 0; mq < 2; ++mq)
    #pragma unroll
    for (int kk = 0; kk < 2; ++kk)
      af[mq][kk] = rdfrag(bufA, wm + (mtb + mq) * 16 + ln15, kk * 4 + l4);
}

DEV void rdB(const unsigned short* bufB, int wn, int ln15, int l4, bf16x8 (&bf)[4][2]) {
  #pragma unroll
  for (int nt = 0; nt < 4; ++nt)
    #pragma unroll
    for (int kk = 0; kk < 2; ++kk)
      bf[nt][kk] = rdfrag(bufB, wn + nt * 16 + ln15, kk * 4 + l4);
}

template <int MTB>
DEV void mfma16(const bf16x8 (&af)[2][2], const bf16x8 (&bf)[4][2], f32x4 (&acc)[8][4]) {
  __builtin_amdgcn_s_setprio(1);
  #pragma unroll
  for (int mq = 0; mq < 2; ++mq)
    #pragma unroll
    for (int nt = 0; nt < 4; ++nt)
      #pragma unroll
      for (int kk = 0; kk < 2; ++kk)
        acc[MTB + mq][nt] = __builtin_amdgcn_mfma_f32_16x16x32_bf16(
            af[mq][kk], bf[nt][kk], acc[MTB + mq][nt], 0, 0, 0);
  __builtin_amdgcn_s_setprio(0);
}

// stage half-tile h (rows [128h,128h+128)) of a 256x64 bf16 tile: 2 ldst16
DEV void stg(unsigned short* buf, const unsigned short* src, int r0, int w,
             int Lrow, int srcC, int k0, int h, int ldK) {
  #pragma unroll
  for (int qq = 0; qq < 2; ++qq) {
    int q = 2 * h + qq;
    ldst16(src + (size_t)(r0 + q * 64 + w * 8 + Lrow) * ldK + (k0 + srcC * 8),
           (char*)buf + ((q * 512 + w * 64) << 4));
  }
}

template <int KD>
DEV void kloop8(const unsigned short* __restrict__ A, const unsigned short* __restrict__ B,
                unsigned short* sh, f32x4 (&acc)[8][4], int m0, int n0, int tid) {
  unsigned short* A0b = sh;
  unsigned short* A1b = sh + 16384;
  unsigned short* B0b = sh + 32768;
  unsigned short* B1b = sh + 49152;
  int w = tid >> 6, lane = tid & 63;
  int wm = (w & 1) * 128, wn = (w >> 1) * 64;
  int ln15 = lane & 15, l4 = lane >> 4;
  int Lrow = lane >> 3;
  int srcC = (lane & 7) ^ (Lrow & 7);
  const int MSK = KD - 1;

  // prologue: A(0)->A0, B(0)->B0, B(1)->B1; keep B(1)'s 4 loads in flight
  stg(A0b, A, m0, w, Lrow, srcC, 0, 0, KD);
  stg(A0b, A, m0, w, Lrow, srcC, 0, 1, KD);
  stg(B0b, B, n0, w, Lrow, srcC, 0, 0, KD);
  stg(B0b, B, n0, w, Lrow, srcC, 0, 1, KD);
  stg(B1b, B, n0, w, Lrow, srcC, 64, 0, KD);
  stg(B1b, B, n0, w, Lrow, srcC, 64, 1, KD);
  VMCNT4;
  bar();

  for (int it = 0; it < KD / 128; ++it) {
    const int k0 = it * 128;
    bf16x8 af[2][2], bf[4][2];

    // ---- tile t0 = 2it (A0b/B0b) ----
    rdB(B0b, wn, ln15, l4, bf);
    rdA(A0b, wm, ln15, l4, 0, af);
    stg(A1b, A, m0, w, Lrow, srcC, k0 + 64, 0, KD);          // A(t1) h0
    bar(); mfma16<0>(af, bf, acc); bar();

    rdA(A0b, wm, ln15, l4, 2, af);
    stg(A1b, A, m0, w, Lrow, srcC, k0 + 64, 1, KD);          // A(t1) h1
    bar(); mfma16<2>(af, bf, acc); bar();

    rdA(A0b, wm, ln15, l4, 4, af);
    stg(B0b, B, n0, w, Lrow, srcC, (k0 + 128) & MSK, 0, KD); // B(t0+2) h0
    bar(); mfma16<4>(af, bf, acc); bar();

    rdA(A0b, wm, ln15, l4, 6, af);
    stg(B0b, B, n0, w, Lrow, srcC, (k0 + 128) & MSK, 1, KD); // B(t0+2) h1
    VMCNT4;                   // completes B(t1)+A(t1); leaves B(t0+2) flying
    bar(); mfma16<6>(af, bf, acc); bar();

    // ---- tile t1 = 2it+1 (A1b/B1b) ----
    rdB(B1b, wn, ln15, l4, bf);
    rdA(A1b, wm, ln15, l4, 0, af);
    stg(A0b, A, m0, w, Lrow, srcC, (k0 + 128) & MSK, 0, KD); // A(t0+2) h0
    bar(); mfma16<0>(af, bf, acc); bar();

    rdA(A1b, wm, ln15, l4, 2, af);
    stg(A0b, A, m0, w, Lrow, srcC, (k0 + 128) & MSK, 1, KD); // A(t0+2) h1
    bar(); mfma16<2>(af, bf, acc); bar();

    rdA(A1b, wm, ln15, l4, 4, af);
    stg(B1b, B, n0, w, Lrow, srcC, (k0 + 192) & MSK, 0, KD); // B(t1+2) h0
    bar(); mfma16<4>(af, bf, acc); bar();

    rdA(A1b, wm, ln15, l4, 6, af);
    stg(B1b, B, n0, w, Lrow, srcC, (k0 + 192) & MSK, 1, KD); // B(t1+2) h1
    VMCNT4;                   // completes A(t0+2); leaves B(t1+2) flying
    bar(); mfma16<6>(af, bf, acc); bar();
  }

  // drain wrapped tail stages before LDS reuse / exit
  VMCNT0;
  bar();
}

// ---------------------------------------------------------------------------
// proj8: merged Q/K/V projection. Blocks [0,1024): K/V (A=ctxb, 65536 rows);
// blocks [1024,1152): Q (A=xb, 16384 rows). K=1024 for all.
// Epilogues: K->RoPE->kb; V->transpose->vtg; Q->RoPE(chunk-row0)->qbuf.
// ---------------------------------------------------------------------------
__global__ __launch_bounds__(512, 2) void proj8(const unsigned short* __restrict__ ctxb,
                                                const unsigned short* __restrict__ xb,
                                                const unsigned short* __restrict__ Wkt,
                                                const unsigned short* __restrict__ Wvt,
                                                const unsigned short* __restrict__ Wqt,
                                                unsigned short* __restrict__ kb,
                                                unsigned short* __restrict__ vtg,
                                                unsigned short* __restrict__ qbuf,
                                                const float* __restrict__ ck,
                                                const float* __restrict__ sk,
                                                const float* __restrict__ cq,
                                                const float* __restrict__ sq) {
  __shared__ unsigned short sh[65536];  // 128 KiB
  int id = blockIdx.x;
  int mode, m0, n0;
  const unsigned short *A, *B;
  if (id < 1024) {
    int x = (id & 7) + 8 * (id >> 5);   // [0,256); 4 (y,z)-siblings same XCD
    int j = (id >> 3) & 3;
    int y = j & 1, z = j >> 1;
    mode = z;                           // 0 = K, 1 = V
    A = ctxb; B = z ? Wvt : Wkt;
    m0 = x << 8; n0 = y << 8;
  } else {
    int t = id - 1024;                  // [0,128)
    int x = (t & 7) + 8 * (t >> 4);     // [0,64); y-siblings same XCD
    int y = (t >> 3) & 1;
    mode = 2;                           // Q
    A = xb; B = Wqt;
    m0 = x << 8; n0 = y << 8;
  }
  int tid = threadIdx.x, w = tid >> 6, lane = tid & 63;
  int wm = (w & 1) * 128, wn = (w >> 1) * 64;
  int ln15 = lane & 15, l4 = lane >> 4;

  f32x4 acc[8][4] = {};
  kloop8<1024>(A, B, sh, acc, m0, n0, tid);

  if (mode == 0) {  // K with RoPE: fi = (m&127)*64 + d
    #pragma unroll
    for (int mt = 0; mt < 8; ++mt)
      #pragma unroll
      for (int r = 0; r < 4; ++r) {
        int m = m0 + wm + mt * 16 + l4 * 4 + r;
        int fib = (m & 127) << 6;
        #pragma unroll
        for (int nt = 0; nt < 4; ++nt) {
          int d = nt * 16 + ln15;
          float partner = acc[mt][nt ^ 2][r];
          float val = acc[mt][nt][r] * ck[fib + d] + (nt < 2 ? -partner : partner) * sk[fib + d];
          kb[(size_t)m * 512 + n0 + wn + d] = f2bf(val);
        }
      }
  } else if (mode == 1) {  // V: transpose through LDS, store vtg[n][m]
    #pragma unroll
    for (int mt = 0; mt < 8; ++mt)
      #pragma unroll
      for (int nt = 0; nt < 4; ++nt)
        #pragma unroll
        for (int r = 0; r < 4; ++r) {
          int ml = wm + mt * 16 + l4 * 4 + r;
          int nl = wn + nt * 16 + ln15;
          int mc = ml >> 3, me = ml & 7;
          *(unsigned short*)((char*)sh + nl * 512 + ((mc ^ (nl & 31)) << 4) + me * 2) =
              f2bf(acc[mt][nt][r]);
        }
    __syncthreads();
    #pragma unroll
    for (int i = 0; i < 16; ++i) {
      int flat = i * 512 + tid;
      int nl = flat >> 5, mc = flat & 31;
      uint4 v = *(const uint4*)((const char*)sh + nl * 512 + ((mc ^ (nl & 31)) << 4));
      *(uint4*)(vtg + (size_t)(n0 + nl) * 65536 + m0 + mc * 8) = v;
    }
  } else {  // Q with RoPE on chunk-row 0
    #pragma unroll
    for (int mt = 0; mt < 8; ++mt)
      #pragma unroll
      for (int nt = 0; nt < 4; ++nt)
        #pragma unroll
        for (int r = 0; r < 4; ++r) {
          int m = m0 + wm + mt * 16 + l4 * 4 + r;
          int n = n0 + wn + nt * 16 + ln15;
          float val = acc[mt][nt][r];
          if ((m & 63) == 0) {
            int d = nt * 16 + ln15;
            float partner = acc[mt][nt ^ 2][r];
            val = val * cq[d] + (nt < 2 ? -partner : partner) * sq[d];
          }
          qbuf[(size_t)m * 512 + n] = f2bf(val);
        }
  }
}

// ---------------------------------------------------------------------------
// out8: out fp32 = obuf(16384x512) @ Wot^T(1024x512) + bias, row-shifted.
// 256 blocks (64 x-panels x 4 y), K=512 on the 8-phase engine.
// ---------------------------------------------------------------------------
__global__ __launch_bounds__(512, 2) void out8(const unsigned short* __restrict__ A,
                                               const unsigned short* __restrict__ B,
                                               const float* __restrict__ bias,
                                               float* __restrict__ out) {
  __shared__ unsigned short sh[65536];
  int id = blockIdx.x;
  int x = (id & 7) + 8 * (id >> 5);   // [0,64)
  int y = (id >> 3) & 3;
  int m0 = x << 8, n0 = y << 8;
  int tid = threadIdx.x, w = tid >> 6, lane = tid & 63;
  int wm = (w & 1) * 128, wn = (w >> 1) * 64;
  int ln15 = lane & 15, l4 = lane >> 4;

  f32x4 acc[8][4] = {};
  kloop8<512>(A, B, sh, acc, m0, n0, tid);

  #pragma unroll
  for (int mt = 0; mt < 8; ++mt)
    #pragma unroll
    for (int nt = 0; nt < 4; ++nt)
      #pragma unroll
      for (int r = 0; r < 4; ++r) {
        int m = m0 + wm + mt * 16 + l4 * 4 + r;
        int n = n0 + wn + nt * 16 + ln15;
        int b = m >> 12, t = m & 4095;
        if (t <= 4032)
          out[((size_t)((b << 12) + t + 63)) * 1024 + n] = acc[mt][nt][r] + bias[n];
      }
}

// ---------------------------------------------------------------------------
// Fused attention per (bc, h) — swapped-QK^T structure.
// LDS: qs 8KB | ks 32KB (becomes ps[q][j] after sync2) | vs 32KB (V^T [d][j]).
// Waves own q-columns [16w,16w+16); P lands [j][q] so row-sums are
// lane-local + shfl_xor(16/32). Two __syncthreads total.
// ---------------------------------------------------------------------------
__global__ __launch_bounds__(256) void attn_kernel(const unsigned short* __restrict__ qb,
                                                   const unsigned short* __restrict__ kb,
                                                   const unsigned short* __restrict__ vtg,
                                                   const float* __restrict__ nullk,
                                                   const float* __restrict__ nullv,
                                                   unsigned short* __restrict__ ob) {
  __shared__ unsigned short qs[64 * 64];    // 8 KB  [q][d]
  __shared__ unsigned short ks[256 * 64];   // 32 KB [j][d]; reused as ps[q][j]
  __shared__ unsigned short vs[64 * 256];   // 32 KB V^T [d][j]
  int id = blockIdx.x;
  int bc = (id & 7) + 8 * (id >> 6);
  int h = (id >> 3) & 7;
  int tid = threadIdx.x, w = tid >> 6, lane = tid & 63;
  int ln15 = lane & 15, l4 = lane >> 4;
  int Lrow = lane >> 3, srcC = (lane & 7) ^ (Lrow & 7);

  // stage Q (2/wave), K (8/wave), V^T (8/wave) — all prefetched upfront
  #pragma unroll
  for (int q8 = 0; q8 < 2; ++q8) {
    int t = w * 2 + q8;
    ldst16(qb + (size_t)(bc * 64 + t * 8 + Lrow) * 512 + h * 64 + srcC * 8, (char*)qs + t * 1024);
  }
  #pragma unroll
  for (int q8 = 0; q8 < 8; ++q8) {
    int t = w * 8 + q8;
    ldst16(kb + (size_t)(bc * 256 + t * 8 + Lrow) * 512 + h * 64 + srcC * 8, (char*)ks + t * 1024);
  }
  #pragma unroll
  for (int q8 = 0; q8 < 8; ++q8) {
    int t = w * 8 + q8;                 // 1KB region = V^T rows 2t, 2t+1
    int dd = t * 2 + (lane >> 5);
    int cl = (lane & 31) ^ (dd & 7);
    ldst16(vtg + (size_t)(h * 64 + dd) * 65536 + bc * 256 + cl * 8, (char*)vs + t * 1024);
  }
  __syncthreads();

  int q = w * 16 + ln15;   // this lane's q-row

  // null-key sim: each l4-group covers 16 d, reduce across groups via shfl
  float ns = 0.f;
  {
    bf16x8 q0 = rdfrag(qs, q, l4 * 2);
    bf16x8 q1 = rdfrag(qs, q, l4 * 2 + 1);
    const float* nkp = nullk + h * 64 + l4 * 16;
    #pragma unroll
    for (int i = 0; i < 8; ++i) ns += bfelem(q0, i) * nkp[i];
    #pragma unroll
    for (int i = 0; i < 8; ++i) ns += bfelem(q1, i) * nkp[8 + i];
    ns += __shfl_xor(ns, 16);
    ns += __shfl_xor(ns, 32);
  }
  float rnull = __expf(ns);

  // QK^T swapped: acc[nt][r] = sim[j = nt*16 + l4*4 + r][q]
  f32x4 acc[16] = {};
  #pragma unroll
  for (int k32 = 0; k32 < 2; ++k32) {
    int c = k32 * 4 + l4;
    bf16x8 bq = rdfrag(qs, q, c);
    #pragma unroll
    for (int nt = 0; nt < 16; ++nt) {
      bf16x8 ak = rdfrag(ks, nt * 16 + ln15, c);
      acc[nt] = __builtin_amdgcn_mfma_f32_16x16x32_bf16(ak, bq, acc[nt], 0, 0, 0);
    }
  }

  // exp + per-q sum (lane-local partial over this l4-group's j residues)
  float s = 0.f;
  #pragma unroll
  for (int nt = 0; nt < 16; ++nt)
    #pragma unroll
    for (int r = 0; r < 4; ++r) {
      float p = __expf(acc[nt][r]);
      acc[nt][r] = p;
      s += p;
    }
  s += __shfl_xor(s, 16);
  s += __shfl_xor(s, 32);
  float rsum = s + rnull;

  __syncthreads();  // all waves done reading ks — safe to overlay ps

  // P -> ps[q][j] (over ks), b64 chunks; swizzle phys16 = cj ^ (q&7)
  #pragma unroll
  for (int nt = 0; nt < 16; ++nt) {
    unsigned int w0 = pk2(acc[nt][0], acc[nt][1]);
    unsigned int w1 = pk2(acc[nt][2], acc[nt][3]);
    int j = nt * 16 + l4 * 4;
    int cj = j >> 3;
    int off = (j & 7) * 2;  // 0 or 8
    uint2 v = {w0, w1};
    *(uint2*)((char*)ks + q * 512 + ((cj ^ (q & 7)) << 4) + off) = v;
  }
  // PV: o^T[d][q] = mfma(A = V^T rows d, B = P cols q); intra-wave RAW on ps
  f32x4 oacc[4] = {};
  #pragma unroll
  for (int kk = 0; kk < 8; ++kk) {
    int c = kk * 4 + l4;
    bf16x8 bp = rdfrag512(ks, q, c);
    #pragma unroll
    for (int nt = 0; nt < 4; ++nt) {
      bf16x8 av = rdfrag512(vs, nt * 16 + ln15, c);
      oacc[nt] = __builtin_amdgcn_mfma_f32_16x16x32_bf16(av, bp, oacc[nt], 0, 0, 0);
    }
  }

  // epilogue: o = (oacc + rnull*nullv)/rsum ; packed 8B stores
  float inv = 1.0f / rsum;
  #pragma unroll
  for (int nt = 0; nt < 4; ++nt) {
    const float* nvp = nullv + h * 64 + nt * 16 + l4 * 4;
    float4 nv4 = *(const float4*)nvp;
    float o0 = (oacc[nt][0] + rnull * nv4.x) * inv;
    float o1 = (oacc[nt][1] + rnull * nv4.y) * inv;
    float o2 = (oacc[nt][2] + rnull * nv4.z) * inv;
    float o3 = (oacc[nt][3] + rnull * nv4.w) * inv;
    uint2 v = {pk2(o0, o1), pk2(o2, o3)};
    *(uint2*)(ob + ((size_t)(bc * 64 + q) * 8 + h) * 64 + nt * 16 + l4 * 4) = v;
  }
}

// ---------------------------------------------------------------------------
extern "C" void kernel_launch(void* const* d_in, const int* in_sizes, int n_in,
                              void* d_out, int out_size, void* d_ws, size_t ws_size,
                              hipStream_t stream) {
  const float* x = (const float*)d_in[0];
  const float* ctx = (const float*)d_in[1];
  const float* qpe = (const float*)d_in[2];
  const float* kpe = (const float*)d_in[3];
  const float* Wq = (const float*)d_in[4];
  const float* Wk = (const float*)d_in[5];
  const float* Wv = (const float*)d_in[6];
  const float* Wo = (const float*)d_in[7];
  const float* bo = (const float*)d_in[8];
  const float* nk = (const float*)d_in[9];
  const float* nv = (const float*)d_in[10];
  float* out = (float*)d_out;
  char* ws = (char*)d_ws;

  unsigned short* Wqt  = (unsigned short*)(ws + 0);          // 1 MB
  unsigned short* Wkt  = (unsigned short*)(ws + 1048576);    // 1 MB
  unsigned short* Wvt  = (unsigned short*)(ws + 2097152);    // 1 MB
  unsigned short* Wot  = (unsigned short*)(ws + 3145728);    // 1 MB
  float* cosk = (float*)(ws + 4194304);                      // 32 KB
  float* sink = (float*)(ws + 4227072);                      // 32 KB
  float* cosq = (float*)(ws + 4259840);                      // 256 B
  float* sinq = (float*)(ws + 4260096);                      // 256 B
  unsigned short* qb   = (unsigned short*)(ws + 8388608);    // 16 MB
  unsigned short* kb   = (unsigned short*)(ws + 25165824);   // 64 MB
  unsigned short* vtg  = (unsigned short*)(ws + 92274688);   // 64 MB (V^T [512][65536])
  unsigned short* obuf = (unsigned short*)(ws + 159383552);  // 16 MB
  unsigned short* xb   = (unsigned short*)(ws + 176160768);  // 32 MB (shifted x, bf16)
  unsigned short* ctxb = (unsigned short*)(ws + 209715200);  // 128 MB
  // peak ws use: ~344 MB (ws is 1 GiB per harness fill evidence)

  prep_k<<<796, 256, 0, stream>>>(Wq, Wk, Wv, Wo, qpe, kpe, Wqt, Wkt, Wvt, Wot,
                                  cosk, sink, cosq, sinq, out);

  cast_all<<<40960, 256, 0, stream>>>(ctx, x, ctxb, xb);

  // Q+K+V projections, one 8-phase launch (K/V: 1024 blocks, Q: 128 blocks)
  proj8<<<1152, 512, 0, stream>>>(ctxb, xb, Wkt, Wvt, Wqt, kb, vtg, qb,
                                  cosk, sink, cosq, sinq);

  attn_kernel<<<2048, 256, 0, stream>>>(qb, kb, vtg, nk, nv, obuf);

  // Output: (16384x512)@(512x1024) + bias, shifted rows
  out8<<<256, 512, 0, stream>>>(obuf, Wot, bo, out);
}